// Round 6
// baseline (10353.832 us; speedup 1.0000x reference)
//
#include <hip/hip_runtime.h>
#include <math.h>

#define TT   256
#define BB   1024
#define YDIM 32
#define HDIM 1024
#define RDIM 512

typedef __attribute__((ext_vector_type(8))) short frag8;
typedef __attribute__((ext_vector_type(4))) float f32x4;
typedef unsigned char u8;

// ---------------- workspace layout (bytes) ----------------
#define OFF_NLL   ((size_t)0)
#define OFF_HAF   ((size_t)4096)                      // fp32 h0 x2
#define SZ_HF     ((size_t)BB*RDIM*4)
#define OFF_HBF   (OFF_HAF + 2*SZ_HF)                 // fp32 h1 x2
#define SZ_H16    ((size_t)BB*RDIM*2)
#define OFF_HA16  (OFF_HBF + 2*SZ_HF)                 // bf16 h0 x2
#define OFF_HB16  (OFF_HA16 + 2*SZ_H16)               // bf16 h1 x2
#define SZ_H8     ((size_t)BB*RDIM)
#define OFF_HB8   (OFF_HB16 + 2*SZ_H16)               // fp8 h1 x2 (D1's A)
#define SZ_D8     ((size_t)BB*HDIM)
#define OFF_D18   (OFF_HB8 + 2*SZ_H8)                 // fp8 d1 x2
#define OFF_D28   (OFF_D18 + 2*SZ_D8)                 // fp8 d2 x2
#define OFF_Y16   (OFF_D28 + 2*SZ_D8)                 // bf16 y
#define OFF_WG0I  (OFF_Y16 + (size_t)TT*BB*YDIM*2)    // [1536][32] bf16 (permRow)
#define OFF_WG0H  (OFF_WG0I + (size_t)1536*YDIM*2)    // [1536][512]
#define OFF_WG1I  (OFF_WG0H + (size_t)1536*RDIM*2)
#define OFF_WG1H  (OFF_WG1I + (size_t)1536*RDIM*2)
#define OFF_WD1F8 (OFF_WG1H + (size_t)1536*RDIM*2)    // fp8 [1024][512]
#define OFF_WD2F8 (OFF_WD1F8 + (size_t)HDIM*RDIM)     // fp8 [1024][1024]
#define OFF_WMSF8 (OFF_WD2F8 + (size_t)HDIM*HDIM)     // fp8 [64][1024]
#define OFF_BI0   (OFF_WMSF8 + (size_t)64*HDIM)
#define OFF_BH0   (OFF_BI0 + 1536*4)
#define OFF_BI1   (OFF_BH0 + 1536*4)
#define OFF_BH1   (OFF_BI1 + 1536*4)

__device__ __forceinline__ short f2bf(float f) {
  union { float f; unsigned u; } v; v.f = f;
  unsigned r = (v.u + 0x7fffu + ((v.u >> 16) & 1u)) >> 16;
  return (short)r;
}
__device__ __forceinline__ void cvt8(const float* s, short* d) {
  float4 a = *(const float4*)s;
  float4 b = *(const float4*)(s + 4);
  frag8 v;
  v[0]=f2bf(a.x); v[1]=f2bf(a.y); v[2]=f2bf(a.z); v[3]=f2bf(a.w);
  v[4]=f2bf(b.x); v[5]=f2bf(b.y); v[6]=f2bf(b.z); v[7]=f2bf(b.w);
  *(frag8*)d = v;
}
__device__ __forceinline__ u8 f2fp8(float x) {
  return (u8)(__builtin_amdgcn_cvt_pk_fp8_f32(x, x, 0, false) & 0xff);
}
__device__ __forceinline__ void cvt8f8(const float* s, u8* d) {
  float4 a = *(const float4*)s;
  float4 b = *(const float4*)(s + 4);
  int lo = __builtin_amdgcn_cvt_pk_fp8_f32(a.x, a.y, 0, false);
  lo = __builtin_amdgcn_cvt_pk_fp8_f32(a.z, a.w, lo, true);
  int hi = __builtin_amdgcn_cvt_pk_fp8_f32(b.x, b.y, 0, false);
  hi = __builtin_amdgcn_cvt_pk_fp8_f32(b.z, b.w, hi, true);
  ((int*)d)[0] = lo; ((int*)d)[1] = hi;
}
// round-2-validated: packed row n' = q*48 + g*16 + u  <->  src row g*512 + q*16 + u
__device__ __forceinline__ int permRow(int n) {
  int q = n / 48, r = n - 48 * q, g = r >> 4, u = r & 15;
  return g * 512 + q * 16 + u;
}
__device__ __forceinline__ float sigf(float x) { return 1.0f / (1.0f + expf(-x)); }

__device__ __forceinline__ void gload16(const void* g, void* l) {
  __builtin_amdgcn_global_load_lds(
      (const __attribute__((address_space(1))) void*)g,
      (__attribute__((address_space(3))) void*)l, 16, 0, 0);
}
__device__ __forceinline__ void waitvm(int n) {
  // simm16: vmcnt[3:0]=n, expcnt=7 (no wait), lgkmcnt=15 (no wait)
  switch (n) {   // builtin needs a compile-time constant
    case 0: __builtin_amdgcn_s_waitcnt(0xF70); break;
    case 3: __builtin_amdgcn_s_waitcnt(0xF73); break;
    case 4: __builtin_amdgcn_s_waitcnt(0xF74); break;
    default: __builtin_amdgcn_s_waitcnt(0xF75); break;  // 5
  }
}

// ======== triple-buffered bf16 GRU K-loop (64B rows = K32 bf16) ========
// A: bf16 [*, ldaB bytes], 128 rows from m0. B: permRow-packed 192-row slice.
// acc[4][2][4]: [a-frag][unit16-grp][col 0=r,1=z,2=ni,3=nh]; n-gate -> col NSEL.
template<int NSEL>
__device__ __forceinline__ void pipe_gru(
    const u8* __restrict__ A, int ldaB, int m0,
    const u8* __restrict__ B, int ldbB, int nk,
    u8* lds, f32x4 (*acc)[2][4], int tid)
{
  constexpr int BUFB = (128 + 192) * 64;   // 20480 B per buffer
  constexpr int NPS  = 5;                  // per-wave loads per stage
  const int l = tid & 63, w = tid >> 6, u = l & 15, quad = l >> 4;
  const int wm = (w & 1) * 64, glb = (w >> 1) * 2;

  auto stage = [&](int kc) {
    u8* buf = lds + (kc % 3) * BUFB;
    const int kB = kc << 6;
    for (int c = (w << 6); c < 512; c += 256) {
      int p = c + l, r = p >> 2, q = (p & 3) ^ (r & 3);
      gload16(A + (size_t)(m0 + r) * ldaB + kB + (q << 4), buf + (c << 4));
    }
    u8* bb = buf + 8192;
    for (int c = (w << 6); c < 768; c += 256) {
      int p = c + l, r = p >> 2, q = (p & 3) ^ (r & 3);
      gload16(B + (size_t)r * ldbB + kB + (q << 4), bb + (c << 4));
    }
  };

  stage(0);
  if (nk > 1) stage(1);
  for (int kc = 0; kc < nk; ++kc) {
    waitvm((kc + 1 < nk) ? NPS : 0);       // chunk kc landed; kc+1 stays in flight
    __builtin_amdgcn_s_barrier();
    if (kc + 2 < nk) stage(kc + 2);
    const u8* base = lds + (kc % 3) * BUFB;
    const u8* bb = base + 8192;
    const int ao = (quad ^ (u & 3)) << 4;
    frag8 a[4], b[2][3];
#pragma unroll
    for (int i = 0; i < 4; ++i)
      a[i] = *(const frag8*)(base + (wm + (i << 4) + u) * 64 + ao);
#pragma unroll
    for (int g = 0; g < 2; ++g)
#pragma unroll
      for (int f = 0; f < 3; ++f)
        b[g][f] = *(const frag8*)(bb + ((glb + g) * 48 + f * 16 + u) * 64 + ao);
#pragma unroll
    for (int i = 0; i < 4; ++i)
#pragma unroll
      for (int g = 0; g < 2; ++g) {
        acc[i][g][0]    = __builtin_amdgcn_mfma_f32_16x16x32_bf16(a[i], b[g][0], acc[i][g][0], 0, 0, 0);
        acc[i][g][1]    = __builtin_amdgcn_mfma_f32_16x16x32_bf16(a[i], b[g][1], acc[i][g][1], 0, 0, 0);
        acc[i][g][NSEL] = __builtin_amdgcn_mfma_f32_16x16x32_bf16(a[i], b[g][2], acc[i][g][NSEL], 0, 0, 0);
      }
  }
  __syncthreads();   // full drain before LDS reuse by caller
}

// ======== triple-buffered fp8 K-loop (64B rows = K64 fp8) ========
template<int MF, int NF, int BROWS>
__device__ __forceinline__ void pipe_f8(
    const u8* __restrict__ A, int ldaB, int m0,
    const u8* __restrict__ B, int ldbB, int nk,
    int wm, int wn, u8* lds, f32x4 (*acc)[NF], int tid)
{
  constexpr int BUFB = (128 + BROWS) * 64;
  constexpr int NPS  = (128 + BROWS) / 64;
  const int l = tid & 63, w = tid >> 6, u = l & 15, quad = l >> 4;

  auto stage = [&](int kc) {
    u8* buf = lds + (kc % 3) * BUFB;
    const int kB = kc << 6;
    for (int c = (w << 6); c < 512; c += 256) {
      int p = c + l, r = p >> 2, q = (p & 3) ^ (r & 3);
      gload16(A + (size_t)(m0 + r) * ldaB + kB + (q << 4), buf + (c << 4));
    }
    u8* bb = buf + 8192;
    for (int c = (w << 6); c < BROWS * 4; c += 256) {
      int p = c + l, r = p >> 2, q = (p & 3) ^ (r & 3);
      gload16(B + (size_t)r * ldbB + kB + (q << 4), bb + (c << 4));
    }
  };

  stage(0);
  if (nk > 1) stage(1);
  for (int kc = 0; kc < nk; ++kc) {
    waitvm((kc + 1 < nk) ? NPS : 0);
    __builtin_amdgcn_s_barrier();
    if (kc + 2 < nk) stage(kc + 2);
    const u8* base = lds + (kc % 3) * BUFB;
    const u8* bb = base + 8192;
#pragma unroll
    for (int kk2 = 0; kk2 < 2; ++kk2) {
      const int unit = (kk2 << 1) + (quad >> 1);
      const int ao = (((unit ^ (u & 3)) << 4)) + ((quad & 1) << 3);
      long a[MF], b[NF];
#pragma unroll
      for (int i = 0; i < MF; ++i)
        a[i] = *(const long*)(base + (wm + (i << 4) + u) * 64 + ao);
#pragma unroll
      for (int f = 0; f < NF; ++f)
        b[f] = *(const long*)(bb + (wn + (f << 4) + u) * 64 + ao);
#pragma unroll
      for (int i = 0; i < MF; ++i)
#pragma unroll
        for (int f = 0; f < NF; ++f)
          acc[i][f] = __builtin_amdgcn_mfma_f32_16x16x32_fp8_fp8(a[i], b[f], acc[i][f], 0, 0, 0);
    }
  }
  __syncthreads();
}

// ======== GRU tile: 128 rows x 64 units, two bf16 passes ========
__device__ void gru6(int mb, int nb,
    const u8* Ax, int ldaxB, int nkx,
    const u8* Ah,
    const u8* Wgi, int ldwiB,
    const u8* Wgh,
    const float* bi, const float* bh,
    const float* hold, float* hout, short* h16out, u8* h8out,
    u8* lds, int tid)
{
  const int w = tid >> 6, l = tid & 63, u = l & 15, quad = l >> 4;
  const int wm = (w & 1) * 64;
  f32x4 zero = {0.f, 0.f, 0.f, 0.f};
  f32x4 acc[4][2][4];
#pragma unroll
  for (int i = 0; i < 4; ++i)
#pragma unroll
    for (int g = 0; g < 2; ++g)
#pragma unroll
      for (int c = 0; c < 4; ++c) acc[i][g][c] = zero;

  pipe_gru<2>(Ax, ldaxB, mb * 128, Wgi, ldwiB, nkx, lds, acc, tid);   // x: n -> ni
  pipe_gru<3>(Ah, RDIM * 2, mb * 128, Wgh, RDIM * 2, 16, lds, acc, tid); // h: n -> nh

#pragma unroll
  for (int g = 0; g < 2; ++g) {
    const int gl = (w >> 1) * 2 + g;
    const int npg = nb * 192 + gl * 48 + u;
    const float bir = bi[npg], biz = bi[npg + 16], bin = bi[npg + 32];
    const float bhr = bh[npg], bhz = bh[npg + 16], bhn = bh[npg + 32];
    const int unit = nb * 64 + gl * 16 + u;
#pragma unroll
    for (int i = 0; i < 4; ++i)
#pragma unroll
      for (int j = 0; j < 4; ++j) {
        int row = mb * 128 + wm + 16 * i + quad * 4 + j;
        float rr = sigf((acc[i][g][0][j] + bir) + bhr);
        float zz = sigf((acc[i][g][1][j] + biz) + bhz);
        float nn = tanhf((acc[i][g][2][j] + bin) + rr * (acc[i][g][3][j] + bhn));
        float ho = hold[(size_t)row * RDIM + unit];
        float hv = (1.f - zz) * nn + zz * ho;
        hout[(size_t)row * RDIM + unit] = hv;
        h16out[(size_t)row * RDIM + unit] = f2bf(hv);
        if (h8out) h8out[(size_t)row * RDIM + unit] = f2fp8(hv);
      }
  }
}

// ======== decoder Linear+ReLU 128x128 (fp8) ========
__device__ void dec_f8(int mb, int nb, const u8* A, int ldaB, int nk,
                       const u8* W, int ldbB, const float* bias, u8* outp,
                       u8* lds, int tid)
{
  f32x4 zero = {0.f, 0.f, 0.f, 0.f};
  f32x4 acc[4][4];
#pragma unroll
  for (int i = 0; i < 4; ++i)
#pragma unroll
    for (int f = 0; f < 4; ++f) acc[i][f] = zero;
  const int w = tid >> 6, l = tid & 63, u = l & 15, quad = l >> 4;
  const int wm = (w & 1) * 64, wn = (w >> 1) * 64;
  pipe_f8<4, 4, 128>(A, ldaB, mb * 128, W, ldbB, nk, wm, wn, lds, acc, tid);
  const int colb = nb * 128 + wn + u;
  float bv[4];
#pragma unroll
  for (int f = 0; f < 4; ++f) bv[f] = bias[colb + 16 * f];
#pragma unroll
  for (int i = 0; i < 4; ++i)
#pragma unroll
    for (int f = 0; f < 4; ++f)
#pragma unroll
      for (int j = 0; j < 4; ++j) {
        int row = mb * 128 + wm + 16 * i + quad * 4 + j;
        float v = acc[i][f][j] + bv[f];
        if (v < 0.f) v = 0.f;
        outp[(size_t)row * HDIM + colb + 16 * f] = f2fp8(v);
      }
}

// ======== mean/std + gaussian NLL (fp8 GEMM) ========
__device__ void ms_f8(int mb, int tstep, const u8* d2p, const u8* Wms,
                      const float* mbias, const float* sbias, const float* y,
                      float* nll, u8* lds, int tid)
{
  f32x4 zero = {0.f, 0.f, 0.f, 0.f};
  f32x4 acc[2][4];
#pragma unroll
  for (int i = 0; i < 2; ++i)
#pragma unroll
    for (int f = 0; f < 4; ++f) acc[i][f] = zero;
  const int w = tid >> 6, l = tid & 63, u = l & 15, quad = l >> 4;
  pipe_f8<2, 4, 64>(d2p, HDIM, mb * 128, Wms, HDIM, 16, w * 32, 0, lds, acc, tid);
  float lsum = 0.f;
#pragma unroll
  for (int i = 0; i < 2; ++i)
#pragma unroll
    for (int j = 0; j < 4; ++j) {
      int row = mb * 128 + w * 32 + 16 * i + quad * 4 + j;
      const float* yr = y + ((size_t)tstep * BB + row) * YDIM;
#pragma unroll
      for (int f = 0; f < 2; ++f) {
        int c = 16 * f + u;
        float m  = acc[i][f][j] + mbias[c];
        float sp = acc[i][f + 2][j] + sbias[c];
        float sg = (sp > 20.f) ? sp : log1pf(expf(sp));
        float dv = (yr[c] - m) / sg;
        lsum += dv * dv + 2.f * logf(sg) + 1.8378770664093453f;
      }
    }
  lsum *= 0.5f;
#pragma unroll
  for (int o = 32; o; o >>= 1) lsum += __shfl_xor(lsum, o);
  if (l == 0) atomicAdd(nll, lsum);
}

// ---------------- prepack ----------------
__global__ __launch_bounds__(256) void prepack_kernel(
    const float* y, const float* dw1, const float* dw2,
    const float* mw, const float* sw,
    const float* wih0, const float* whh0, const float* bih0, const float* bhh0,
    const float* wih1, const float* whh1, const float* bih1, const float* bhh1,
    char* __restrict__ ws)
{
  const size_t g = (size_t)blockIdx.x * 256 + threadIdx.x;
  const size_t N = (size_t)gridDim.x * 256;
  float4 z4 = {0.f, 0.f, 0.f, 0.f};
  float4* hz = (float4*)(ws + OFF_HAF);
  for (size_t i = g; i < (size_t)4 * BB * RDIM / 4; i += N) hz[i] = z4;
  int4 zi = {0, 0, 0, 0};
  int4* h16z = (int4*)(ws + OFF_HA16);
  for (size_t i = g; i < (size_t)4 * BB * RDIM / 8; i += N) h16z[i] = zi;
  int4* h8z = (int4*)(ws + OFF_HB8);
  for (size_t i = g; i < (size_t)2 * BB * RDIM / 16; i += N) h8z[i] = zi;
  if (g == 0) *(float*)(ws + OFF_NLL) = 0.f;

  short* y16  = (short*)(ws + OFF_Y16);
  short* Wg0i = (short*)(ws + OFF_WG0I);
  short* Wg0h = (short*)(ws + OFF_WG0H);
  short* Wg1i = (short*)(ws + OFF_WG1I);
  short* Wg1h = (short*)(ws + OFF_WG1H);
  u8* Wd1f8 = (u8*)(ws + OFF_WD1F8);
  u8* Wd2f8 = (u8*)(ws + OFF_WD2F8);
  u8* Wmsf8 = (u8*)(ws + OFF_WMSF8);
  float* bi0  = (float*)(ws + OFF_BI0);
  float* bh0  = (float*)(ws + OFF_BH0);
  float* bi1  = (float*)(ws + OFF_BI1);
  float* bh1  = (float*)(ws + OFF_BH1);

  for (size_t s = g; s < (size_t)TT * BB * YDIM / 8; s += N)
    cvt8(y + s * 8, y16 + s * 8);

  for (size_t s = g; s < (size_t)1536 * RDIM / 8; s += N) {
    int row = (int)(s >> 6), seg = (int)(s & 63) << 3;
    int pr = permRow(row);
    cvt8(whh0 + (size_t)pr * RDIM + seg, Wg0h + (size_t)row * RDIM + seg);
    cvt8(wih1 + (size_t)pr * RDIM + seg, Wg1i + (size_t)row * RDIM + seg);
    cvt8(whh1 + (size_t)pr * RDIM + seg, Wg1h + (size_t)row * RDIM + seg);
  }
  for (size_t s = g; s < (size_t)1536 * YDIM / 8; s += N) {
    int row = (int)(s >> 2), seg = (int)(s & 3) << 3;
    cvt8(wih0 + (size_t)permRow(row) * YDIM + seg, Wg0i + (size_t)row * YDIM + seg);
  }
  for (size_t s = g; s < (size_t)HDIM * RDIM / 8; s += N)
    cvt8f8(dw1 + s * 8, Wd1f8 + s * 8);
  for (size_t s = g; s < (size_t)HDIM * HDIM / 8; s += N)
    cvt8f8(dw2 + s * 8, Wd2f8 + s * 8);
  for (size_t s = g; s < (size_t)64 * HDIM / 8; s += N) {
    int row = (int)(s >> 7), seg = (int)(s & 127) << 3;
    const float* src = (row < 32) ? (mw + (size_t)row * HDIM + seg)
                                  : (sw + (size_t)(row - 32) * HDIM + seg);
    cvt8f8(src, Wmsf8 + (size_t)row * HDIM + seg);
  }
  for (size_t s = g; s < 1536; s += N) {
    int pr = permRow((int)s);
    bi0[s] = bih0[pr]; bh0[s] = bhh0[pr];
    bi1[s] = bih1[pr]; bh1[s] = bhh1[pr];
  }
}

// ---------------- one pipeline phase (grid = 264) ----------------
__global__ __launch_bounds__(256, 2) void phase_kernel(
    int p, const float* __restrict__ y,
    const float* db1, const float* db2, const float* mbias, const float* sbias,
    char* __restrict__ ws)
{
  __shared__ __align__(16) u8 lds[61440];   // 60 KB: GRU 3 x 20KB triple-buffer
  const int tid = threadIdx.x;
  const int t = blockIdx.x;
  const int cur = p & 1, prv = cur ^ 1;

  float* hAf = (float*)(ws + OFF_HAF);
  float* hBf = (float*)(ws + OFF_HBF);
  short* hA16 = (short*)(ws + OFF_HA16);
  short* hB16 = (short*)(ws + OFF_HB16);
  u8* hB8 = (u8*)(ws + OFF_HB8);
  u8* d18 = (u8*)(ws + OFF_D18);
  u8* d28 = (u8*)(ws + OFF_D28);
  const u8* y16 = (const u8*)(ws + OFF_Y16);

  float* hAfc = hAf + (size_t)cur * BB * RDIM;
  float* hAfp = hAf + (size_t)prv * BB * RDIM;
  float* hBfc = hBf + (size_t)cur * BB * RDIM;
  float* hBfp = hBf + (size_t)prv * BB * RDIM;
  short* hA16c = hA16 + (size_t)cur * BB * RDIM;
  short* hA16p = hA16 + (size_t)prv * BB * RDIM;
  short* hB16c = hB16 + (size_t)cur * BB * RDIM;
  short* hB16p = hB16 + (size_t)prv * BB * RDIM;
  u8* hB8c = hB8 + (size_t)cur * BB * RDIM;
  u8* hB8p = hB8 + (size_t)prv * BB * RDIM;
  u8* d1c = d18 + (size_t)cur * BB * HDIM;
  u8* d1p = d18 + (size_t)prv * BB * HDIM;
  u8* d2c = d28 + (size_t)cur * BB * HDIM;
  u8* d2p = d28 + (size_t)prv * BB * HDIM;

  const u8* Wg0i = (const u8*)(ws + OFF_WG0I);
  const u8* Wg0h = (const u8*)(ws + OFF_WG0H);
  const u8* Wg1i = (const u8*)(ws + OFF_WG1I);
  const u8* Wg1h = (const u8*)(ws + OFF_WG1H);
  const u8* Wd1f8 = (const u8*)(ws + OFF_WD1F8);
  const u8* Wd2f8 = (const u8*)(ws + OFF_WD2F8);
  const u8* Wmsf8 = (const u8*)(ws + OFF_WMSF8);
  const float* bi0  = (const float*)(ws + OFF_BI0);
  const float* bh0  = (const float*)(ws + OFF_BH0);
  const float* bi1  = (const float*)(ws + OFF_BI1);
  const float* bh1  = (const float*)(ws + OFF_BH1);
  float* nllp = (float*)(ws + OFF_NLL);

  if (t < 64) {                     // GRU1: x = h0_{p-1}, h = h1_{p-2} -> h1_{p-1}
    if (p >= 1 && p <= 255) {
      int mb = t >> 3, nb = t & 7;
      gru6(mb, nb,
           (const u8*)hA16p, RDIM * 2, 16,
           (const u8*)hB16p,
           Wg1i + (size_t)nb * 192 * RDIM * 2, RDIM * 2,
           Wg1h + (size_t)nb * 192 * RDIM * 2,
           bi1, bh1, hBfp, hBfc, hB16c, hB8c, lds, tid);
    }
  } else if (t < 128) {             // GRU0: x = y[p], h = h0_{p-1} -> h0_p
    if (p <= 255) {
      int q = t - 64, mb = q >> 3, nb = q & 7;
      gru6(mb, nb,
           y16 + (size_t)p * BB * YDIM * 2, YDIM * 2, 1,
           (const u8*)hA16p,
           Wg0i + (size_t)nb * 192 * YDIM * 2, YDIM * 2,
           Wg0h + (size_t)nb * 192 * RDIM * 2,
           bi0, bh0, hAfp, hAfc, hA16c, (u8*)0, lds, tid);
    }
  } else if (t < 192) {             // D1 for step p-1 (A = fp8 h1)
    if (p >= 1 && p <= 256) {
      int q = t - 128, mb = q >> 3, nb = q & 7;
      dec_f8(mb, nb, hB8p, RDIM, 8, Wd1f8 + (size_t)nb * 128 * RDIM, RDIM,
             db1, d1c, lds, tid);
    }
  } else if (t < 256) {             // D2 for step p-2
    if (p >= 2 && p <= 257) {
      int q = t - 192, mb = q >> 3, nb = q & 7;
      dec_f8(mb, nb, d1p, HDIM, 16, Wd2f8 + (size_t)nb * 128 * HDIM, HDIM,
             db2, d2c, lds, tid);
    }
  } else {                          // MS/nll for step p-3
    if (p >= 3 && p <= 258) {
      ms_f8(t - 256, p - 3, d2p, Wmsf8, mbias, sbias, y, nllp, lds, tid);
    }
  }
}

__global__ void finish_kernel(float* out, const char* ws)
{
  if (threadIdx.x == 0 && blockIdx.x == 0)
    out[0] = *(const float*)(ws + OFF_NLL);
}

extern "C" void kernel_launch(void* const* d_in, const int* in_sizes, int n_in,
                              void* d_out, int out_size, void* d_ws, size_t ws_size,
                              hipStream_t stream) {
  (void)in_sizes; (void)n_in; (void)out_size; (void)ws_size;
  const float* y    = (const float*)d_in[0];
  const float* dw1  = (const float*)d_in[1];
  const float* db1  = (const float*)d_in[2];
  const float* dw2  = (const float*)d_in[3];
  const float* db2  = (const float*)d_in[4];
  const float* mw   = (const float*)d_in[5];
  const float* mbias= (const float*)d_in[6];
  const float* sw   = (const float*)d_in[7];
  const float* sbias= (const float*)d_in[8];
  const float* wih0 = (const float*)d_in[9];
  const float* whh0 = (const float*)d_in[10];
  const float* bih0 = (const float*)d_in[11];
  const float* bhh0 = (const float*)d_in[12];
  const float* wih1 = (const float*)d_in[13];
  const float* whh1 = (const float*)d_in[14];
  const float* bih1 = (const float*)d_in[15];
  const float* bhh1 = (const float*)d_in[16];
  char* ws = (char*)d_ws;
  float* out = (float*)d_out;

  prepack_kernel<<<256, 256, 0, stream>>>(y, dw1, dw2, mw, sw,
                                          wih0, whh0, bih0, bhh0,
                                          wih1, whh1, bih1, bhh1, ws);
  for (int p = 0; p < 259; ++p)
    phase_kernel<<<264, 256, 0, stream>>>(p, y, db1, db2, mbias, sbias, ws);
  finish_kernel<<<1, 1, 0, stream>>>(out, ws);
}